// Round 7
// baseline (153.211 us; speedup 1.0000x reference)
//
#include <hip/hip_runtime.h>

// FilteredNoiseGenerator: B=32, t=4000, nbands=65, framesize=80, L_fir=129, L=208
// out[b,p] = sum_{f,m} x[b,f,m]*w[b,f,tau], tau = (p+64) - 80f - m in [0,128]
// P1 (firwin) = GEMM vs fixed matrix M (MFMA f16, M in d_ws, frag-order).
// R15: window-rotation closure (R14 flat -> trip-head-latency theory wrong; the
//     residual is window-bookkeeping movs + the serial array-shift spine).
//     Window redefined: C (dw @ wb-4) + E[8] (even pairs @ wb-2+2k) + O[8]
//     (odd pairs @ wb-3+2j). Slide -8 f16 = shift-4 on 8-arrays = PERIOD 2 ->
//     loop hand-unrolled x2 with named SSA vars (TRIP macro): all shifts are
//     operand renaming, zero movs; only backedge phis remain (coalescable).
//     Per trip: 4 b32 w + 2 b64 x (1-trip prefetch) + 4 alignbit + 40 fdot2.
//     Same operand values, same per-acc fdot2 order -> bit-identical.

#define NT 256
#define X_STRIDE 84        // f16 x row stride; 168 B rows (8B-aligned), 42 dw -> 2-way banks (free)
#define XPAD 8             // front pad so x prefetch (down to xr[-8]) is in-bounds
#define W_STRIDE 154       // f16 w row; 77 dw/row, gcd(77,32)=1 -> conflict-free
#define W_P 24             // w[tau] at wr[W_P+tau]; tau in [0,128]; zeros outside
#define NSLOT 35           // frames f0-2 .. f0+32
#define WTOT_H 5416        // 34*154 + 178 = 5414 max pad write; 16B-aligned total
#define XTOT_H 2948        // XPAD + 35*84

typedef _Float16 f16x8 __attribute__((ext_vector_type(8)));
typedef _Float16 f16x4 __attribute__((ext_vector_type(4)));
typedef _Float16 h2 __attribute__((ext_vector_type(2)));
typedef float f32x4 __attribute__((ext_vector_type(4)));

union U32H2 { unsigned u; h2 h; };
static __device__ __forceinline__ h2 mid_h2(h2 lo, h2 hi) {    // (lo.y, hi.x)
  U32H2 a, b; a.h = lo; b.h = hi;
  U32H2 o; o.u = __builtin_amdgcn_alignbit(b.u, a.u, 16);
  return o.h;
}

// ---- init: M in MFMA B-operand frag order (R6-proven). frag (nt,ks) of 27;
// lane holds B[k = ks*32 + (lane>>4)*8 + j][n = nt*16 + (lane&15)], j=0..7.
__global__ void __launch_bounds__(256)
minit_kernel(_Float16* __restrict__ M) {
  const float TP = 6.28318530717958647692f / 129.f;
  int i = blockIdx.x * 256 + threadIdx.x;      // 54*256 = 13824 = 27*512 exactly
  int frag = i >> 9;
  int off  = i & 511;
  int lane = off >> 3, j = off & 7;
  int nt = frag / 3, ks = frag - 3 * (frag / 3);
  int n = nt * 16 + (lane & 15);
  int k = ks * 32 + (lane >> 4) * 8 + j;
  float v = 0.f;
  if (n <= 128 && k <= 64) {
    float hann = 0.5f - 0.5f * __cosf((float)n * TP);
    float sc = (k == 0 ? 1.f : 2.f) * (1.f / 129.f);
    int e = (k * (n - 64)) % 129; if (e < 0) e += 129;   // exact arg reduction
    v = hann * sc * __cosf((float)e * TP);
  }
  M[i] = (_Float16)v;
}

__global__ void __launch_bounds__(NT, 8)
fng_kernel(const float* __restrict__ Hg_, const float* __restrict__ Ng_,
           float* __restrict__ Og_, const _Float16* __restrict__ Mg) {
  __shared__ __align__(16) _Float16 sWh[WTOT_H];   // 10,832 B firwin f16
  __shared__ __align__(16) _Float16 sXh[XTOT_H];   //  5,896 B x f16, REVERSED rows

  const int t  = threadIdx.x;
  const int bx = blockIdx.x;     // 0..124 (32 output-frames each)
  const int b  = blockIdx.y;     // 0..31
  const int f0 = bx * 32;

  const int wv   = t >> 6;
  const int lane = t & 63;

  // ---- issue H loads FIRST (waves 0-2): raw f32 in regs; the wait lands at
  // P1's converts, after P0a/P0c have executed under the load latency.
  float c0[8], c1[8];
  float s64 = 0.f;
  bool  va  = false;
  {
    if (wv < 3) {
      const int quad = lane >> 4;
      const int l15  = lane & 15;
      const int fr   = f0 - 2 + wv * 16 + l15;
      va = (fr >= 0 && fr < 4000);
      const int frc  = va ? fr : 0;               // clamped addr, always valid
      const float* hr = Hg_ + (size_t)b * 260000 + (size_t)frc * 65;
      __builtin_memcpy(c0, &hr[quad * 8], 32);    // 4B-aligned safe
      __builtin_memcpy(c1, &hr[32 + quad * 8], 32);
      s64 = hr[64];
    }
  }

  // ---- P0a: zero ONLY the pad cells of sWh (disjoint from P1 data writes).
  // Pads: [0,24) front of row 0; for c in 0..34 the 25-cell run
  // [c*154+153, c*154+178). 24 + 35*25 = 899 cells.
  {
#pragma unroll
    for (int it = 0; it < 4; ++it) {
      int j = t + NT * it;
      if (j < 24) {
        sWh[j] = (_Float16)0.f;
      } else if (j < 899) {
        int jj = j - 24;
        int c = jj / 25, o = jj - 25 * c;
        sWh[c * W_STRIDE + 153 + o] = (_Float16)0.f;
      }
    }
  }

  // ---- P0c: noise -> sXh REVERSED f16 (xr[u] = 2*noise[79-u]-1) ----
  {
    const float* Ng = Ng_ + (size_t)b * 320000;
#pragma unroll
    for (int j = 0; j < 3; ++j) {
      int q = t + NT * j;
      if (q < NSLOT * 20) {
        int fi = q / 20, qm = q - 20 * fi;
        int fr = f0 - 2 + fi;
        f16x4 o = {(_Float16)0.f, (_Float16)0.f, (_Float16)0.f, (_Float16)0.f};
        if (fr >= 0 && fr < 4000) {
          float4 v = *(const float4*)&Ng[(size_t)fr * 80 + 4 * qm];
          o.x = (_Float16)(2.f * v.w - 1.f);   // x[4qm+3]
          o.y = (_Float16)(2.f * v.z - 1.f);   // x[4qm+2]
          o.z = (_Float16)(2.f * v.y - 1.f);   // x[4qm+1]
          o.w = (_Float16)(2.f * v.x - 1.f);   // x[4qm]
        }
        *(f16x4*)&sXh[XPAD + fi * X_STRIDE + (76 - 4 * qm)] = o;   // 8B-aligned
      }
    }
  }

  // ---- P1: firwin = H x M^T via MFMA 16x16x32 f16; A from the early loads ----
  // Rows outside [0,4000) -> zero A-frag. k in [65,96): M rows are zero ->
  // zeros supplied. C rows (frames) >= NSLOT discarded by guard.
  {
    if (wv < 3) {
      const int quad = lane >> 4;
      const int l15  = lane & 15;
      const int mt   = wv;
      if (!va) {
#pragma unroll
        for (int j = 0; j < 8; ++j) { c0[j] = 0.f; c1[j] = 0.f; }
        s64 = 0.f;
      }
      f16x8 a0, a1, a2;
#pragma unroll
      for (int j = 0; j < 8; ++j) {
        a0[j] = (_Float16)c0[j];
        a1[j] = (_Float16)c1[j];
        a2[j] = (_Float16)0.f;
      }
      if (quad == 0) a2[0] = (_Float16)s64;       // col 64; cols 65..71 zero

#pragma unroll 3
      for (int nt = 0; nt < 9; ++nt) {
        f32x4 acc = {0.f, 0.f, 0.f, 0.f};
        f16x8 b0 = ((const f16x8*)Mg)[(nt * 3 + 0) * 64 + lane];
        f16x8 b1 = ((const f16x8*)Mg)[(nt * 3 + 1) * 64 + lane];
        f16x8 b2 = ((const f16x8*)Mg)[(nt * 3 + 2) * 64 + lane];
        acc = __builtin_amdgcn_mfma_f32_16x16x32_f16(a0, b0, acc, 0, 0, 0);
        acc = __builtin_amdgcn_mfma_f32_16x16x32_f16(a1, b1, acc, 0, 0, 0);
        acc = __builtin_amdgcn_mfma_f32_16x16x32_f16(a2, b2, acc, 0, 0, 0);
        const int n = nt * 16 + l15;
        if (n <= 128) {
          const int fb = mt * 16 + quad * 4;
#pragma unroll
          for (int r = 0; r < 4; ++r) {
            int frame = fb + r;
            if (frame < NSLOT) sWh[frame * W_STRIDE + W_P + n] = (_Float16)acc[r];
          }
        }
      }
    }
  }
  __syncthreads();   // single barrier: pads + x + w all visible

  // ------- P2: gather convolution, period-2 named-register window -------
  // Window at tap base wb: Cw = dw @ wb-4; E[k] = even pair @ wb-2+2k (k=0..7);
  // O[j] = odd pair @ wb-3+2j (j=0..7). PAIR(K): even K -> E[(K+2)/2],
  // odd K -> O[(K+3)/2]. Slide wb-=8: E'[0..2]=new, E'[3]=Cw, E'[4..7]=E[0..3];
  // O'[0..3]=new mids, O'[4..7]=O[0..3]; Cw'=new. Same operand values and
  // per-acc fdot2 order as R14 -> bit-identical output.
  {
    const int col = t & 31;
    const int pb  = t >> 5;
    const int e   = 64 + 10 * pb;
    const int qq  = (e >= 80) ? 1 : 0;
    const int D   = e - 80 * qq;                    // per half-wave uniform, even
    float acc[10];
#pragma unroll
    for (int i = 0; i < 10; ++i) acc[i] = 0.f;

#define FD(a, x, p) a = __builtin_amdgcn_fdot2(x, p, a, false)
// burst for one trip: i = 9..0, per i: xA*PAIR(i+3), xB*PAIR(i+1),
// xC*PAIR(i-1), xD*PAIR(i-3)  (mapping verified per-slot).
#define BURST(q0, q1, E0,E1,E2,E3,E4,E5,E6,E7, O0,O1,O2,O3,O4,O5,O6,O7)      \
  do {                                                                        \
    h2 xD_; xD_.x = (q0).x; xD_.y = (q0).y;   /* (x7,x6) */                   \
    h2 xC_; xC_.x = (q0).z; xC_.y = (q0).w;   /* (x5,x4) */                   \
    h2 xB_; xB_.x = (q1).x; xB_.y = (q1).y;   /* (x3,x2) */                   \
    h2 xA_; xA_.x = (q1).z; xA_.y = (q1).w;   /* (x1,x0) */                   \
    FD(acc[9], xA_, E7); FD(acc[9], xB_, E6); FD(acc[9], xC_, E5); FD(acc[9], xD_, E4); \
    FD(acc[8], xA_, O7); FD(acc[8], xB_, O6); FD(acc[8], xC_, O5); FD(acc[8], xD_, O4); \
    FD(acc[7], xA_, E6); FD(acc[7], xB_, E5); FD(acc[7], xC_, E4); FD(acc[7], xD_, E3); \
    FD(acc[6], xA_, O6); FD(acc[6], xB_, O5); FD(acc[6], xC_, O4); FD(acc[6], xD_, O3); \
    FD(acc[5], xA_, E5); FD(acc[5], xB_, E4); FD(acc[5], xC_, E3); FD(acc[5], xD_, E2); \
    FD(acc[4], xA_, O5); FD(acc[4], xB_, O4); FD(acc[4], xC_, O3); FD(acc[4], xD_, O2); \
    FD(acc[3], xA_, E4); FD(acc[3], xB_, E3); FD(acc[3], xC_, E2); FD(acc[3], xD_, E1); \
    FD(acc[2], xA_, O4); FD(acc[2], xB_, O3); FD(acc[2], xC_, O2); FD(acc[2], xD_, O1); \
    FD(acc[1], xA_, E3); FD(acc[1], xB_, E2); FD(acc[1], xC_, E1); FD(acc[1], xD_, E0); \
    FD(acc[0], xA_, O3); FD(acc[0], xB_, O2); FD(acc[0], xC_, O1); FD(acc[0], xD_, O0); \
  } while (0)
// one trip: prefetch next-trip w dwords + x quads, burst current window,
// build next-trip low odd pairs. W_P=24 => wb-12 >= 0 for every trip.
#define TRIP(Ci, E0,E1,E2,E3,E4,E5,E6,E7, O0,O1,O2,O3,O4,O5,O6,O7, q0,q1,    \
             Co, F0,F1,F2, R0,R1,R2,R3, P0,P1)                                \
  Co = *(const h2*)&wr[wb - 12];                                              \
  F0 = *(const h2*)&wr[wb - 10];                                              \
  F1 = *(const h2*)&wr[wb - 8];                                               \
  F2 = *(const h2*)&wr[wb - 6];                                               \
  xp -= 8;                                                                    \
  P0 = *(const f16x4*)&xp[0];                                                 \
  P1 = *(const f16x4*)&xp[4];                                                 \
  BURST(q0, q1, E0,E1,E2,E3,E4,E5,E6,E7, O0,O1,O2,O3,O4,O5,O6,O7);            \
  R0 = mid_h2(Co, F0);                                                        \
  R1 = mid_h2(F0, F1);                                                        \
  R2 = mid_h2(F1, F2);                                                        \
  R3 = mid_h2(F2, Ci);                                                        \
  wb -= 8;

#pragma unroll 1
    for (int g = 2; g >= -1; --g) {                 // source frame F - g
      const int dlt = D + 80 * g;                   // even
      int Ulo = (dlt - 128) >> 3; if (Ulo < 0) Ulo = 0;
      int Uhi = (dlt + 9) >> 3;   if (Uhi > 9) Uhi = 9;
      if (Ulo > Uhi) continue;
      const int slot = col + qq - g + 2;            // 0..34
      const _Float16* wr = &sWh[slot * W_STRIDE];
      const _Float16* xr = &sXh[XPAD + slot * X_STRIDE];
      int wb = 20 + dlt - 8 * Ulo;                  // even, >= 12 on all trips

      // head: Cw + E[0..7] (9 b32) + O[0..7] (8 alignbit) + first x quads
      h2 Ca = *(const h2*)&wr[wb - 4];
      h2 a0 = *(const h2*)&wr[wb - 2];
      h2 a1 = *(const h2*)&wr[wb + 0];
      h2 a2 = *(const h2*)&wr[wb + 2];
      h2 a3 = *(const h2*)&wr[wb + 4];
      h2 a4 = *(const h2*)&wr[wb + 6];
      h2 a5 = *(const h2*)&wr[wb + 8];
      h2 a6 = *(const h2*)&wr[wb + 10];
      h2 a7 = *(const h2*)&wr[wb + 12];
      h2 u0 = mid_h2(Ca, a0);
      h2 u1 = mid_h2(a0, a1);
      h2 u2 = mid_h2(a1, a2);
      h2 u3 = mid_h2(a2, a3);
      h2 u4 = mid_h2(a3, a4);
      h2 u5 = mid_h2(a4, a5);
      h2 u6 = mid_h2(a5, a6);
      h2 u7 = mid_h2(a6, a7);
      const _Float16* xp = &xr[72 - 8 * Ulo];
      f16x4 qa0 = *(const f16x4*)&xp[0];
      f16x4 qa1 = *(const f16x4*)&xp[4];

      int U = Ulo;
      for (;;) {
        h2 Cb, b0, b1, b2, v0, v1, v2, v3;
        f16x4 qb0, qb1;
        TRIP(Ca, a0,a1,a2,a3,a4,a5,a6,a7, u0,u1,u2,u3,u4,u5,u6,u7, qa0,qa1,
             Cb, b0,b1,b2, v0,v1,v2,v3, qb0,qb1)
        if (++U > Uhi) break;

        h2 Cc, c0_, c1_, c2_, w0, w1, w2, w3;
        f16x4 qc0, qc1;
        TRIP(Cb, b0,b1,b2,Ca, a0,a1,a2,a3, v0,v1,v2,v3, u0,u1,u2,u3, qb0,qb1,
             Cc, c0_,c1_,c2_, w0,w1,w2,w3, qc0,qc1)
        if (++U > Uhi) break;

        // re-establish A-names for the next double-trip (pure phi-copies):
        // E = [c0_,c1_,c2_, Cb, b0,b1,b2, Ca]; O = [w0..3, v0..3]; Cw = Cc.
        a7 = Ca; Ca = Cc;
        a3 = Cb;
        a4 = b0; a5 = b1; a6 = b2;
        a0 = c0_; a1 = c1_; a2 = c2_;
        u4 = v0; u5 = v1; u6 = v2; u7 = v3;
        u0 = w0; u1 = w1; u2 = w2; u3 = w3;
        qa0 = qc0; qa1 = qc1;
      }
    }
#undef TRIP
#undef BURST
#undef FD

    // exactly-once writeout: u0 = 80*col + 10*pb (even -> float2 stores)
    float* Ob = Og_ + (size_t)b * 320000 + 2560 * bx + 80 * col + 10 * pb;
#pragma unroll
    for (int s = 0; s < 5; ++s) {
      float2 v; v.x = acc[2 * s]; v.y = acc[2 * s + 1];
      *(float2*)&Ob[2 * s] = v;
    }
  }
}

extern "C" void kernel_launch(void* const* d_in, const int* in_sizes, int n_in,
                              void* d_out, int out_size, void* d_ws, size_t ws_size,
                              hipStream_t stream) {
  const float* H     = (const float*)d_in[0];   // [32,4000,65] fp32
  const float* noise = (const float*)d_in[1];   // [32,4000,80] fp32
  float* out = (float*)d_out;                   // [32,320000] fp32
  _Float16* M = (_Float16*)d_ws;                // 27,648 B of scratch
  (void)in_sizes; (void)n_in; (void)ws_size; (void)out_size;

  minit_kernel<<<54, 256, 0, stream>>>(M);      // rebuilt every call (ws re-poisoned)
  dim3 grid(125, 32, 1);
  fng_kernel<<<grid, NT, 0, stream>>>(H, noise, out, M);
}